// Round 16
// baseline (190.709 us; speedup 1.0000x reference)
//
#include <hip/hip_runtime.h>
#include <math.h>

#define BB 16
#define CC 256
#define C3 768
#define HH 56
#define WW 56
#define HWSZ 3136
#define HEADS 8
#define HD 32
#define EPSF 1e-12f
#define NCHUNK 7
#define SLAB 1088             // 32*32 gram + 32 q-sumsq + 32 k-sumsq

using s16x8 = __attribute__((ext_vector_type(8))) short;
using u16x8 = __attribute__((ext_vector_type(8))) unsigned short;
using u16x4 = __attribute__((ext_vector_type(4))) unsigned short;
using f32x4 = __attribute__((ext_vector_type(4))) float;
using f32x16 = __attribute__((ext_vector_type(16))) float;

__device__ inline unsigned short f2bf(float f) {
    unsigned int u = __float_as_uint(f);
    return (unsigned short)((u + 0x7FFFu + ((u >> 16) & 1u)) >> 16);
}
__device__ inline float bf2f(unsigned short s) {
    return __uint_as_float((unsigned int)s << 16);
}
__device__ inline void gload16(const unsigned short* g, const unsigned short* l) {
    __builtin_amdgcn_global_load_lds(
        (const __attribute__((address_space(1))) void*)g,
        (__attribute__((address_space(3))) void*)l, 16, 0, 0);
}
__device__ inline int bkey(int r) { return (r & 7) ^ ((r >> 2) & 7); }

// ---------------------------------------------------------------------------
// fp32 -> bf16 flat convert (qkv weights). n multiple of 2048; grid n/2048.
// ---------------------------------------------------------------------------
__global__ __launch_bounds__(256)
void cvt_w(const float* __restrict__ A, unsigned short* __restrict__ B)
{
    int i = (blockIdx.x * 256 + threadIdx.x) * 8;
    float4 a = *(const float4*)&A[i];
    float4 b = *(const float4*)&A[i + 4];
    u16x8 o;
    o[0] = f2bf(a.x); o[1] = f2bf(a.y); o[2] = f2bf(a.z); o[3] = f2bf(a.w);
    o[4] = f2bf(b.x); o[5] = f2bf(b.y); o[6] = f2bf(b.z); o[7] = f2bf(b.w);
    *(u16x8*)&B[i] = o;
}

// ---------------------------------------------------------------------------
// qkv GEMM (R9 structure — measured best 58-61 us):
//   tmp[m][n] = sum_k W[m][k] * x[k][n], K=256 in 4 steps of 64.
// In-kernel B-transpose: x fp32 k-major -> regs (ping-pong, next tile loaded
// after barrier) -> bf16 -> ds_write_b128 at granule kr^bkey(n) (measured
// conflict-free). A via gload16 (linear LDS, src XOR row&7). Single 32KB
// buffer, 2 barriers/K-step. Swapped-operand MFMA epilogue -> u16x4 stores.
// grid 2352 (MT=6), no tails.
// ---------------------------------------------------------------------------
__global__ __launch_bounds__(256)
void gemm_qkv(const unsigned short* __restrict__ Ab,
              const float* __restrict__ Xf,
              unsigned short* __restrict__ Yb)
{
    constexpr int MT = 6;
    __shared__ __align__(16) unsigned short S[16384];   // A 16KB + B 16KB
    const int t = threadIdx.x;
    const int w = t >> 6, lane = t & 63;

    const int nwg = (int)gridDim.x;
    const int bid = (int)blockIdx.x;
    const int q8 = nwg >> 3, r8 = nwg & 7;
    const int xcd = bid & 7, idx = bid >> 3;
    const int sw = (xcd < r8 ? xcd * (q8 + 1) : r8 * (q8 + 1) + (xcd - r8) * q8) + idx;
    const int mt = sw % MT, nt = sw / MT;
    const int m0 = mt * 128;
    const int n0 = nt * 128;

    const int rl  = lane >> 3;
    const int gsw = ((lane & 7) ^ rl) << 3;
    const int lr = lane & 15, gq = lane >> 4;
    const int m_off = (w >> 1) * 64, n_off = (w & 1) * 64;

    const unsigned short* GA = Ab + (long)m0 * 256;

    const int nq = t & 31, kr = t >> 5;
    const int nrow = nq * 4;
    const int ng = n0 + nrow;
    const int z0 = ng / HWSZ;
    const int hw = ng - z0 * HWSZ;
    const float* Bf = Xf + (long)z0 * CC * HWSZ + hw;

    f32x4 acc[4][4];
#pragma unroll
    for (int i = 0; i < 4; ++i)
#pragma unroll
        for (int j = 0; j < 4; ++j) acc[i][j] = (f32x4){0.f, 0.f, 0.f, 0.f};

    float4 stg0[8], stg1[8];

#define LOADB(kt, sg)                                                         \
    { _Pragma("unroll")                                                       \
      for (int l = 0; l < 8; ++l)                                             \
          sg[l] = *(const float4*)(Bf + (long)((kt) * 64 + kr * 8 + l) * HWSZ); }

#define WRITEB(sg)                                                            \
    { _Pragma("unroll")                                                       \
      for (int e = 0; e < 4; ++e) {                                           \
          int n = nrow + e;                                                   \
          int g = kr ^ bkey(n);                                               \
          u16x8 v;                                                            \
          _Pragma("unroll")                                                   \
          for (int l = 0; l < 8; ++l) v[l] = f2bf(((const float*)&sg[l])[e]); \
          *(u16x8*)&S[8192 + n * 64 + g * 8] = v;                             \
      } }

#define STAGEA(kt)                                                            \
    { const unsigned short* ga = GA + (kt) * 64;                              \
      _Pragma("unroll")                                                       \
      for (int qq = 0; qq < 4; ++qq) {                                        \
          int R = w * 32 + qq * 8;                                            \
          gload16(ga + (long)(R + rl) * 256 + gsw, S + R * 64);               \
      } }

    LOADB(0, stg0);
#pragma unroll
    for (int kt = 0; kt < 4; ++kt) {
        if (kt & 1) { WRITEB(stg1); } else { WRITEB(stg0); }
        STAGEA(kt);
        __syncthreads();
        if (kt < 3) {
            if (kt & 1) { LOADB(kt + 1, stg0); } else { LOADB(kt + 1, stg1); }
        }
        {
            s16x8 af[4][2], bfr[4][2];
#pragma unroll
            for (int i = 0; i < 4; ++i) {
                int r = m_off + i * 16 + lr;
#pragma unroll
                for (int ks = 0; ks < 2; ++ks)
                    af[i][ks] = *(const s16x8*)&S[r * 64 + (((gq + ks * 4) ^ (r & 7)) << 3)];
            }
#pragma unroll
            for (int j = 0; j < 4; ++j) {
                int r = n_off + j * 16 + lr;
#pragma unroll
                for (int ks = 0; ks < 2; ++ks)
                    bfr[j][ks] = *(const s16x8*)&S[8192 + r * 64 + (((gq + ks * 4) ^ bkey(r)) << 3)];
            }
#pragma unroll
            for (int ks = 0; ks < 2; ++ks)
#pragma unroll
                for (int i = 0; i < 4; ++i)
#pragma unroll
                    for (int j = 0; j < 4; ++j)
                        acc[i][j] = __builtin_amdgcn_mfma_f32_16x16x32_bf16(
                            bfr[j][ks], af[i][ks], acc[i][j], 0, 0, 0);
        }
        __syncthreads();
    }
#undef LOADB
#undef WRITEB
#undef STAGEA

    const int om = lane & 15, on = (lane >> 4) * 4;
    const long Nn = (long)BB * HWSZ;
#pragma unroll
    for (int i = 0; i < 4; ++i) {
        long row = m0 + m_off + i * 16 + om;
#pragma unroll
        for (int j = 0; j < 4; ++j) {
            long col = n0 + n_off + j * 16 + on;
            u16x4 v;
#pragma unroll
            for (int r = 0; r < 4; ++r) v[r] = f2bf(acc[i][j][r]);
            *(u16x4*)&Yb[row * Nn + col] = v;
        }
    }
}

// ---------------------------------------------------------------------------
// Transpose v: dw16 v-section [b][k=256][3136] bf16 -> vT[b][n][256].
// grid (49, 4, BB), block 256.
// ---------------------------------------------------------------------------
__global__ __launch_bounds__(256)
void cvt_v_T(const unsigned short* __restrict__ dw, unsigned short* __restrict__ VT)
{
    __shared__ float L[64][65];
    const int t = threadIdx.x;
    const int n0 = blockIdx.x * 64;
    const int c0 = blockIdx.y * 64;
    const long bofV = ((long)blockIdx.z * C3 + 2 * CC) * HWSZ;
    const long bofT = (long)blockIdx.z * HWSZ * CC;
#pragma unroll
    for (int l = 0; l < 4; ++l) {
        int idx = l * 256 + t;
        int ch = idx >> 4, n4 = (idx & 15) * 4;
        u16x4 v = *(const u16x4*)&dw[bofV + (long)(c0 + ch) * HWSZ + n0 + n4];
        L[n4 + 0][ch] = bf2f(v[0]); L[n4 + 1][ch] = bf2f(v[1]);
        L[n4 + 2][ch] = bf2f(v[2]); L[n4 + 3][ch] = bf2f(v[3]);
    }
    __syncthreads();
#pragma unroll
    for (int l = 0; l < 2; ++l) {
        int idx = l * 256 + t;
        int r = idx >> 3, c8 = (idx & 7) * 8;
        u16x8 o;
#pragma unroll
        for (int e = 0; e < 8; ++e) o[e] = f2bf(L[r][c8 + e]);
        *(u16x8*)&VT[bofT + (long)(n0 + r) * CC + c0 + c8] = o;
    }
}

// ---------------------------------------------------------------------------
// Proj GEMM (R11 structure — measured 42 us, at fp32-out write floor):
//   out[z][m][n] = sum_k M[z][m][k] * vT[z][n][k]. gload16 both operands,
//   128x128 tile, BK=64, 64KB dbuf. Swapped-operand epilogue, float4 stores.
// grid (50, 16), tail guarded.
// ---------------------------------------------------------------------------
__global__ __launch_bounds__(256)
void gemm_proj(const unsigned short* __restrict__ Ab,
               const unsigned short* __restrict__ Bb,
               float* __restrict__ Yv)
{
    constexpr int MT = 2;
    __shared__ __align__(16) unsigned short S[32768];
    const int t = threadIdx.x;
    const int w = t >> 6, lane = t & 63;

    const int nwg = (int)gridDim.x;
    const int bid = (int)blockIdx.x;
    const int q8 = nwg >> 3, r8 = nwg & 7;
    const int xcd = bid & 7, idx = bid >> 3;
    const int sw = (xcd < r8 ? xcd * (q8 + 1) : r8 * (q8 + 1) + (xcd - r8) * q8) + idx;
    const int mt = sw % MT, nt = sw / MT;
    const int m0 = mt * 128;
    const int n0 = nt * 128;
    const int z = (int)blockIdx.y;

    const int rl  = lane >> 3;
    const int gsw = ((lane & 7) ^ rl) << 3;
    const int lr = lane & 15, gq = lane >> 4;
    const int m_off = (w >> 1) * 64, n_off = (w & 1) * 64;

    const unsigned short* GA = Ab + (long)z * CC * CC + (long)m0 * 256;
    const unsigned short* GB = Bb + (long)z * HWSZ * CC + (long)n0 * 256;

    f32x4 acc[4][4];
#pragma unroll
    for (int i = 0; i < 4; ++i)
#pragma unroll
        for (int j = 0; j < 4; ++j) acc[i][j] = (f32x4){0.f, 0.f, 0.f, 0.f};

#define STAGE(buf, kt)                                                        \
    {                                                                         \
        const unsigned short* L = S + (buf) * 16384;                          \
        const unsigned short* ga = GA + (kt) * 64;                            \
        const unsigned short* gb = GB + (kt) * 64;                            \
        _Pragma("unroll")                                                     \
        for (int qq = 0; qq < 4; ++qq) {                                      \
            int R = w * 32 + qq * 8;                                          \
            gload16(ga + (long)(R + rl) * 256 + gsw, L + R * 64);             \
            gload16(gb + (long)(R + rl) * 256 + gsw, L + 8192 + R * 64);      \
        }                                                                     \
    }

    STAGE(0, 0);
    __syncthreads();
#pragma unroll
    for (int kt = 0; kt < 4; ++kt) {
        if (kt < 3) STAGE((kt + 1) & 1, kt + 1);
        const unsigned short* L = S + (kt & 1) * 16384;
        s16x8 af[4][2], bf[4][2];
#pragma unroll
        for (int i = 0; i < 4; ++i) {
            int r = m_off + i * 16 + lr;
#pragma unroll
            for (int ks = 0; ks < 2; ++ks)
                af[i][ks] = *(const s16x8*)&L[r * 64 + (((gq + ks * 4) ^ (r & 7)) << 3)];
        }
#pragma unroll
        for (int j = 0; j < 4; ++j) {
            int r = n_off + j * 16 + lr;
#pragma unroll
            for (int ks = 0; ks < 2; ++ks)
                bf[j][ks] = *(const s16x8*)&L[8192 + r * 64 + (((gq + ks * 4) ^ (r & 7)) << 3)];
        }
#pragma unroll
        for (int ks = 0; ks < 2; ++ks)
#pragma unroll
            for (int i = 0; i < 4; ++i)
#pragma unroll
                for (int j = 0; j < 4; ++j)
                    acc[i][j] = __builtin_amdgcn_mfma_f32_16x16x32_bf16(
                        bf[j][ks], af[i][ks], acc[i][j], 0, 0, 0);
        __syncthreads();
    }
#undef STAGE

    const int om = lane & 15, on = (lane >> 4) * 4;
    float* Yb = Yv + (long)z * CC * HWSZ;
#pragma unroll
    for (int i = 0; i < 4; ++i) {
        int row = m0 + m_off + i * 16 + om;
#pragma unroll
        for (int j = 0; j < 4; ++j) {
            int col = n0 + n_off + j * 16 + on;
            if (col < HWSZ)
                *(float4*)&Yb[(long)row * HWSZ + col] =
                    make_float4(acc[i][j][0], acc[i][j][1],
                                acc[i][j][2], acc[i][j][3]);
        }
    }
}

// ---------------------------------------------------------------------------
// Depthwise 3x3, pad 1 — LDS plane kernel, 4 px/thread via float4 row reads.
// ---------------------------------------------------------------------------
__global__ __launch_bounds__(256)
void dwconv3x3(const unsigned short* __restrict__ X,
               const float* __restrict__ Wd,
               unsigned short* __restrict__ Y,
               long Nn)
{
    __shared__ float P[HWSZ];
    const int ch = blockIdx.x;
    const int z = blockIdx.y;
    const int t = threadIdx.x;
    const unsigned short* xc = X + (long)ch * Nn + (long)z * HWSZ;
#pragma unroll
    for (int l = 0; l < 3; ++l) {
        int q4 = l * 256 + t;
        u16x4 v = *(const u16x4*)&xc[q4 * 4];
        *(float4*)&P[q4 * 4] =
            make_float4(bf2f(v[0]), bf2f(v[1]), bf2f(v[2]), bf2f(v[3]));
    }
    if (t < 16) {
        int q4 = 768 + t;
        u16x4 v = *(const u16x4*)&xc[q4 * 4];
        *(float4*)&P[q4 * 4] =
            make_float4(bf2f(v[0]), bf2f(v[1]), bf2f(v[2]), bf2f(v[3]));
    }
    float w9[9];
#pragma unroll
    for (int q = 0; q < 9; ++q) w9[q] = Wd[ch * 9 + q];
    __syncthreads();

    unsigned short* yc = Y + ((long)z * C3 + ch) * HWSZ;
    const int lane = t & 63;
#pragma unroll
    for (int l = 0; l < 4; ++l) {
        int g4 = l * 256 + t;
        if (g4 < 784) {
            int qi = g4 / 14, qj = g4 - qi * 14;
            float o0 = 0.f, o1 = 0.f, o2 = 0.f, o3 = 0.f;
#pragma unroll
            for (int di = 0; di < 3; ++di) {
                int ii = qi + di - 1;
                if ((unsigned)ii >= HH) continue;
                const float* Pr = &P[ii * WW + qj * 4];
                float4 v = *(const float4*)Pr;
                float lf = __shfl_up(v.w, 1);
                float rt = __shfl_down(v.x, 1);
                if (lane == 0 && qj != 0)   lf = Pr[-1];
                if (lane == 63 && qj != 13) rt = Pr[4];
                if (qj == 0)  lf = 0.f;
                if (qj == 13) rt = 0.f;
                const float wL = w9[di * 3 + 0], wC = w9[di * 3 + 1], wR = w9[di * 3 + 2];
                o0 += wL * lf  + wC * v.x + wR * v.y;
                o1 += wL * v.x + wC * v.y + wR * v.z;
                o2 += wL * v.y + wC * v.z + wR * v.w;
                o3 += wL * v.z + wC * v.w + wR * rt;
            }
            u16x4 ov;
            ov[0] = f2bf(o0); ov[1] = f2bf(o1); ov[2] = f2bf(o2); ov[3] = f2bf(o3);
            *(u16x4*)&yc[g4 * 4] = ov;
        }
    }
}

// ---------------------------------------------------------------------------
// Gram via MFMA: partial Q.K^T + diag norms per (chunk, h, b). grid (7,8,16).
// ---------------------------------------------------------------------------
__global__ __launch_bounds__(256)
void gram_mfma(const unsigned short* __restrict__ dw, float* __restrict__ gram)
{
    __shared__ float Sred[SLAB];
    const int c = blockIdx.x, h = blockIdx.y, b = blockIdx.z;
    const int t = threadIdx.x;
    const int w = t >> 6, lane = t & 63;
    const unsigned short* qb = dw + ((long)b * C3 + h * HD) * HWSZ;
    const unsigned short* kb = dw + ((long)b * C3 + CC + h * HD) * HWSZ;

    for (int l = t; l < SLAB; l += 256) Sred[l] = 0.f;

    const int row = lane & 31;
    const int hi  = lane >> 5;
    const long rbase = (long)row * HWSZ + hi * 8;

    f32x16 aqk, aqq, akk;
#pragma unroll
    for (int i = 0; i < 16; ++i) { aqk[i] = 0.f; aqq[i] = 0.f; akk[i] = 0.f; }

#pragma unroll
    for (int s = 0; s < 7; ++s) {
        int p0 = (c * 28 + w * 7 + s) * 16;
        s16x8 qf = *(const s16x8*)&qb[rbase + p0];
        s16x8 kf = *(const s16x8*)&kb[rbase + p0];
        aqk = __builtin_amdgcn_mfma_f32_32x32x16_bf16(qf, kf, aqk, 0, 0, 0);
        aqq = __builtin_amdgcn_mfma_f32_32x32x16_bf16(qf, qf, aqq, 0, 0, 0);
        akk = __builtin_amdgcn_mfma_f32_32x32x16_bf16(kf, kf, akk, 0, 0, 0);
    }
    __syncthreads();

#pragma unroll
    for (int r = 0; r < 16; ++r) {
        int rowd = (r & 3) + 8 * (r >> 2) + 4 * hi;
        atomicAdd(&Sred[rowd * 32 + row], aqk[r]);
    }
    {
        int dreg = (row & 3) | ((row >> 3) << 2);
        bool has = ((row >> 2) & 1) == hi;
        float qd = has ? aqq[dreg] : 0.f;
        float kd = has ? akk[dreg] : 0.f;
        qd += __shfl_xor(qd, 32);
        kd += __shfl_xor(kd, 32);
        if (hi == 0) {
            atomicAdd(&Sred[1024 + row], qd);
            atomicAdd(&Sred[1056 + row], kd);
        }
    }
    __syncthreads();
    float* slab = gram + (((long)c * BB + b) * HEADS + h) * SLAB;
    for (int l = t; l < SLAB; l += 256) slab[l] = Sred[l];
}

// ---------------------------------------------------------------------------
// Sum slabs, normalize, temperature, softmax over j; write TRANSPOSED
// attn: atT[b][h][j][i] (fp32) for the mprep MFMA B-operand. grid (8,16).
// ---------------------------------------------------------------------------
__global__ __launch_bounds__(1024)
void attn_finish(const float* __restrict__ gram,
                 const float* __restrict__ temp,
                 float* __restrict__ attnT)
{
    __shared__ float nrm[64];
    const int h = blockIdx.x, b = blockIdx.y;
    const int t = threadIdx.x;
    const long sbase = ((long)b * HEADS + h) * SLAB;
    const long cstr  = (long)BB * HEADS * SLAB;
    if (t < 64) {
        float s = 0.f;
#pragma unroll
        for (int c = 0; c < NCHUNK; ++c) s += gram[c * cstr + sbase + 1024 + t];
        nrm[t] = fmaxf(sqrtf(s), EPSF);
    }
    __syncthreads();
    const int i = t >> 5, j = t & 31;
    float s = 0.f;
#pragma unroll
    for (int c = 0; c < NCHUNK; ++c) s += gram[c * cstr + sbase + i * 32 + j];
    s *= temp[h] / (nrm[i] * nrm[32 + j]);
    float mx = s;
    mx = fmaxf(mx, __shfl_xor(mx, 1));
    mx = fmaxf(mx, __shfl_xor(mx, 2));
    mx = fmaxf(mx, __shfl_xor(mx, 4));
    mx = fmaxf(mx, __shfl_xor(mx, 8));
    mx = fmaxf(mx, __shfl_xor(mx, 16));
    float e = expf(s - mx);
    float sum = e;
    sum += __shfl_xor(sum, 1); sum += __shfl_xor(sum, 2);
    sum += __shfl_xor(sum, 4); sum += __shfl_xor(sum, 8);
    sum += __shfl_xor(sum, 16);
    attnT[(((long)b * HEADS + h) * HD + j) * HD + i] = e / sum;
}

// ---------------------------------------------------------------------------
// M[b] = Wp x blockdiag(attn). grid (16), block 256. Output bf16 [256][256].
// ---------------------------------------------------------------------------
__global__ __launch_bounds__(256)
void mprep(const float* __restrict__ Wp,
           const float* __restrict__ atT,
           unsigned short* __restrict__ Mm)
{
    const int zb = blockIdx.x;
    const int t = threadIdx.x, w = t >> 6, lane = t & 63;
    const int lr = lane & 15, gq = lane >> 4;
    const int m_base = w * 64;
    const float* atb = atT + (long)zb * HEADS * HD * HD;
    unsigned short* Mb = Mm + (long)zb * CC * CC;

#pragma unroll
    for (int h = 0; h < 8; ++h) {
        s16x8 bf[2];
#pragma unroll
        for (int jt = 0; jt < 2; ++jt) {
            const float* src = atb + (long)(h * 32 + jt * 16 + lr) * 32 + gq * 8;
            float4 a = *(const float4*)src;
            float4 b = *(const float4*)(src + 4);
            s16x8 v;
            v[0] = (short)f2bf(a.x); v[1] = (short)f2bf(a.y);
            v[2] = (short)f2bf(a.z); v[3] = (short)f2bf(a.w);
            v[4] = (short)f2bf(b.x); v[5] = (short)f2bf(b.y);
            v[6] = (short)f2bf(b.z); v[7] = (short)f2bf(b.w);
            bf[jt] = v;
        }
#pragma unroll
        for (int i = 0; i < 4; ++i) {
            const float* src = Wp + (long)(m_base + i * 16 + lr) * 256 + h * 32 + gq * 8;
            float4 a = *(const float4*)src;
            float4 b = *(const float4*)(src + 4);
            s16x8 af;
            af[0] = (short)f2bf(a.x); af[1] = (short)f2bf(a.y);
            af[2] = (short)f2bf(a.z); af[3] = (short)f2bf(a.w);
            af[4] = (short)f2bf(b.x); af[5] = (short)f2bf(b.y);
            af[6] = (short)f2bf(b.z); af[7] = (short)f2bf(b.w);
#pragma unroll
            for (int jt = 0; jt < 2; ++jt) {
                f32x4 acc = (f32x4){0.f, 0.f, 0.f, 0.f};
                acc = __builtin_amdgcn_mfma_f32_16x16x32_bf16(af, bf[jt], acc, 0, 0, 0);
#pragma unroll
                for (int r = 0; r < 4; ++r)
                    Mb[(long)(m_base + i * 16 + gq * 4 + r) * 256
                       + h * 32 + jt * 16 + lr] = f2bf(acc[r]);
            }
        }
    }
}

// ---------------------------------------------------------------------------
extern "C" void kernel_launch(void* const* d_in, const int* in_sizes, int n_in,
                              void* d_out, int out_size, void* d_ws, size_t ws_size,
                              hipStream_t stream)
{
    const float* x      = (const float*)d_in[0];
    const float* w_qkv  = (const float*)d_in[1];
    const float* w_dw   = (const float*)d_in[2];
    const float* w_proj = (const float*)d_in[3];
    const float* temp   = (const float*)d_in[4];
    float* out = (float*)d_out;
    float* ws  = (float*)d_ws;

    const size_t atF = (size_t)BB * HEADS * HD * HD;           // 131,072 f
    const size_t grF = (size_t)NCHUNK * BB * HEADS * SLAB;     // 974,848 f
    const size_t dwE = (size_t)BB * C3 * HWSZ;                 // u16
    const size_t wqE = (size_t)C3 * CC;                        // u16
    const size_t mmE = (size_t)BB * CC * CC;                   // u16
    const size_t vtE = (size_t)BB * HWSZ * CC + 64 * CC;       // u16 (+pad)

    float* atT  = ws;
    float* gram = ws + atF;
    unsigned short* dw16 = (unsigned short*)(ws + atF + grF);
    unsigned short* wqb  = dw16 + dwE;
    unsigned short* Mm   = wqb + wqE;
    unsigned short* vT   = Mm + mmE;
    unsigned short* tmp  = vT + vtE;
    // ~187 MB total

    cvt_w<<<dim3((C3 * CC) / 2048), 256, 0, stream>>>(w_qkv, wqb);

    // qkv: [768 x 50176 x 256], B = x transposed in-kernel (R9 structure).
    gemm_qkv<<<dim3(2352), 256, 0, stream>>>(wqb, x, tmp);

    dwconv3x3<<<dim3(C3, BB), 256, 0, stream>>>(tmp, w_dw, dw16, (long)BB * HWSZ);

    gram_mfma<<<dim3(NCHUNK, HEADS, BB), 256, 0, stream>>>(dw16, gram);
    attn_finish<<<dim3(HEADS, BB), 1024, 0, stream>>>(gram, temp, atT);
    mprep<<<dim3(BB), 256, 0, stream>>>(w_proj, atT, Mm);
    cvt_v_T<<<dim3(49, 4, BB), 256, 0, stream>>>(dw16, vT);

    // proj: per-z [256 x 3136 x 256], A = M[z], B = vT (pre-transposed).
    gemm_proj<<<dim3(50, BB), 256, 0, stream>>>(Mm, vT, out);
}

// Round 17
// 162.317 us; speedup vs baseline: 1.1749x; 1.1749x over previous
//
#include <hip/hip_runtime.h>
#include <math.h>

#define BB 16
#define CC 256
#define C3 768
#define HH 56
#define WW 56
#define HWSZ 3136
#define HEADS 8
#define HD 32
#define EPSF 1e-12f
#define NCHUNK 7
#define SLAB 1088             // 32*32 gram + 32 q-sumsq + 32 k-sumsq

using s16x8 = __attribute__((ext_vector_type(8))) short;
using u16x8 = __attribute__((ext_vector_type(8))) unsigned short;
using u16x4 = __attribute__((ext_vector_type(4))) unsigned short;
using f32x4 = __attribute__((ext_vector_type(4))) float;
using f32x16 = __attribute__((ext_vector_type(16))) float;

__device__ inline unsigned short f2bf(float f) {
    unsigned int u = __float_as_uint(f);
    return (unsigned short)((u + 0x7FFFu + ((u >> 16) & 1u)) >> 16);
}
__device__ inline float bf2f(unsigned short s) {
    return __uint_as_float((unsigned int)s << 16);
}
// B-array row key: spreads banks for BOTH read lanes (r-stride 1) and
// write lanes (n-stride 4).
__device__ inline int bkey(int r) { return (r & 7) ^ ((r >> 2) & 7); }

// ---------------------------------------------------------------------------
// fp32 -> bf16 flat convert (qkv weights). n multiple of 2048; grid n/2048.
// ---------------------------------------------------------------------------
__global__ __launch_bounds__(256)
void cvt_w(const float* __restrict__ A, unsigned short* __restrict__ B)
{
    int i = (blockIdx.x * 256 + threadIdx.x) * 8;
    float4 a = *(const float4*)&A[i];
    float4 b = *(const float4*)&A[i + 4];
    u16x8 o;
    o[0] = f2bf(a.x); o[1] = f2bf(a.y); o[2] = f2bf(a.z); o[3] = f2bf(a.w);
    o[4] = f2bf(b.x); o[5] = f2bf(b.y); o[6] = f2bf(b.z); o[7] = f2bf(b.w);
    *(u16x8*)&B[i] = o;
}

// ---------------------------------------------------------------------------
// GEMM with in-kernel B-transpose: Y[m][n] = sum_k A[m][k] * B[k][n].
// A bf16 [M][256] row-major, staged via gload16 (linear LDS, src XOR row&7).
// B staged k-major global -> regs (ping-pong, loaded 1 iter ahead) -> bf16 ->
// single ds_write_b128 per (thread,e) at granule kr ^ bkey(n): conflict-free.
// Single 32KB buffer, m97 2-barrier loop; LOADB issued right after barrier 1
// so its latency hides under the MFMA phase.
// MODE 0: B = x fp32 [b][256][3136] (n global, z=n/3136); Y = tmp bf16
//         [768][50176]; MT=6, grid 2352.
// MODE 1: B = v bf16 rows of dw16 (per z=blockIdx.y); A = M[z]; Y = out fp32;
//         MT=2, grid (50, 16), tail guarded.
// ---------------------------------------------------------------------------
template<int MODE>
__global__ __launch_bounds__(256, 3)
void gemm_tb(const unsigned short* __restrict__ Ab,
             const void* __restrict__ Bv,
             void* __restrict__ Yv)
{
    constexpr int MT = (MODE == 0) ? 6 : 2;
    __shared__ __align__(16) unsigned short S[16384];   // A 16KB + B 16KB
    const int t = threadIdx.x;
    const int w = t >> 6, lane = t & 63;

    const int nwg = (int)gridDim.x;
    const int bid = (int)blockIdx.x;
    const int q8 = nwg >> 3, r8 = nwg & 7;
    const int xcd = bid & 7, idx = bid >> 3;
    const int sw = (xcd < r8 ? xcd * (q8 + 1) : r8 * (q8 + 1) + (xcd - r8) * q8) + idx;
    const int mt = sw % MT, nt = sw / MT;
    const int m0 = mt * 128;
    const int n0 = nt * 128;
    const int z = (MODE == 1) ? (int)blockIdx.y : 0;

    // A staging (gload16)
    const int rl  = lane >> 3;
    const int gsw = ((lane & 7) ^ rl) << 3;
    // fragment addressing
    const int lr = lane & 15, gq = lane >> 4;
    const int m_off = (w >> 1) * 64, n_off = (w & 1) * 64;

    // B staging: thread (nq, kr): granule kr (8 k), 4 consecutive n
    const int nq = t & 31, kr = t >> 5;
    const int nrow = nq * 4;
    long bz; int hw;
    if (MODE == 0) {
        int ng = n0 + nrow;
        int z0 = ng / HWSZ;
        hw = ng - z0 * HWSZ;
        bz = (long)z0 * CC * HWSZ;
    } else {
        hw = n0 + nrow;
        if (hw > HWSZ - 4) hw = HWSZ - 4;
        bz = ((long)z * C3 + 2 * CC) * HWSZ;
    }

    const unsigned short* GA = Ab + ((MODE == 1) ? (long)z * CC * CC : 0)
                                  + (long)m0 * 256;

    f32x4 acc[4][4];
#pragma unroll
    for (int i = 0; i < 4; ++i)
#pragma unroll
        for (int j = 0; j < 4; ++j) acc[i][j] = (f32x4){0.f, 0.f, 0.f, 0.f};

    u16x4 stg0[8], stg1[8];

#define LOADB(kt, sg)                                                         \
    {                                                                         \
        if (MODE == 0) {                                                      \
            const float* Bf = (const float*)Bv + bz + hw;                     \
            _Pragma("unroll")                                                 \
            for (int l = 0; l < 8; ++l) {                                     \
                float4 v = *(const float4*)(Bf + (long)((kt) * 64 + kr * 8 + l) * HWSZ); \
                u16x4 o; o[0] = f2bf(v.x); o[1] = f2bf(v.y);                  \
                o[2] = f2bf(v.z); o[3] = f2bf(v.w);                           \
                sg[l] = o;                                                    \
            }                                                                 \
        } else {                                                              \
            const unsigned short* Bu = (const unsigned short*)Bv + bz + hw;   \
            _Pragma("unroll")                                                 \
            for (int l = 0; l < 8; ++l)                                       \
                sg[l] = *(const u16x4*)(Bu + (long)((kt) * 64 + kr * 8 + l) * HWSZ); \
        }                                                                     \
    }

    // one b128 per e: full granule (8 u16 along k) for row n at pos kr^bkey(n)
#define WRITEB(sg)                                                            \
    {                                                                         \
        unsigned short* LB = S + 8192;                                        \
        _Pragma("unroll")                                                     \
        for (int e = 0; e < 4; ++e) {                                         \
            int n = nrow + e;                                                 \
            int g = kr ^ bkey(n);                                             \
            u16x8 v;                                                          \
            _Pragma("unroll")                                                 \
            for (int l = 0; l < 8; ++l) v[l] = sg[l][e];                      \
            *(u16x8*)&LB[n * 64 + g * 8] = v;                                 \
        }                                                                     \
    }

#define STAGEA(kt)                                                            \
    {                                                                         \
        const unsigned short* ga = GA + (kt) * 64;                            \
        _Pragma("unroll")                                                     \
        for (int qq = 0; qq < 4; ++qq) {                                      \
            int R = w * 32 + qq * 8;                                          \
            __builtin_amdgcn_global_load_lds(                                 \
                (const __attribute__((address_space(1))) void*)               \
                    (ga + (long)(R + rl) * 256 + gsw),                        \
                (__attribute__((address_space(3))) void*)(S + R * 64),        \
                16, 0, 0);                                                    \
        }                                                                     \
    }

    LOADB(0, stg0);
#pragma unroll
    for (int kt = 0; kt < 4; ++kt) {
        if (kt & 1) { WRITEB(stg1); } else { WRITEB(stg0); }   // waits its loads
        STAGEA(kt);
        __syncthreads();
        if (kt < 3) {                       // issue next B loads; hide under MFMA
            if (kt & 1) { LOADB(kt + 1, stg0); } else { LOADB(kt + 1, stg1); }
        }
        {
            const unsigned short* LA = S;
            const unsigned short* LB = S + 8192;
            s16x8 af[4][2], bf[4][2];
#pragma unroll
            for (int i = 0; i < 4; ++i) {
                int r = m_off + i * 16 + lr;
#pragma unroll
                for (int ks = 0; ks < 2; ++ks)
                    af[i][ks] = *(const s16x8*)&LA[r * 64 + (((gq + ks * 4) ^ (r & 7)) << 3)];
            }
#pragma unroll
            for (int j = 0; j < 4; ++j) {
                int r = n_off + j * 16 + lr;
#pragma unroll
                for (int ks = 0; ks < 2; ++ks)
                    bf[j][ks] = *(const s16x8*)&LB[r * 64 + (((gq + ks * 4) ^ bkey(r)) << 3)];
            }
#pragma unroll
            for (int ks = 0; ks < 2; ++ks)
#pragma unroll
                for (int i = 0; i < 4; ++i)
#pragma unroll
                    for (int j = 0; j < 4; ++j)
                        acc[i][j] = __builtin_amdgcn_mfma_f32_16x16x32_bf16(
                            af[i][ks], bf[j][ks], acc[i][j], 0, 0, 0);
        }
        __syncthreads();
    }
#undef LOADB
#undef WRITEB
#undef STAGEA

    const int orow = (lane >> 4) * 4, ocol = lane & 15;
    if (MODE == 0) {
        unsigned short* Yb = (unsigned short*)Yv;
        const long Nn = (long)BB * HWSZ;
#pragma unroll
        for (int i = 0; i < 4; ++i)
#pragma unroll
            for (int j = 0; j < 4; ++j) {
                long col = n0 + n_off + j * 16 + ocol;
#pragma unroll
                for (int r = 0; r < 4; ++r)
                    Yb[(long)(m0 + m_off + i * 16 + orow + r) * Nn + col] =
                        f2bf(acc[i][j][r]);
            }
    } else {
        float* Yb = (float*)Yv + (long)z * CC * HWSZ;
#pragma unroll
        for (int j = 0; j < 4; ++j) {
            int col = n0 + n_off + j * 16 + ocol;
            if (col < HWSZ) {
#pragma unroll
                for (int i = 0; i < 4; ++i)
#pragma unroll
                    for (int r = 0; r < 4; ++r)
                        Yb[(long)(m0 + m_off + i * 16 + orow + r) * HWSZ + col] =
                            acc[i][j][r];
            }
        }
    }
}

// ---------------------------------------------------------------------------
// Depthwise 3x3, pad 1 — LDS plane kernel, 4 px/thread via float4 row reads.
// ---------------------------------------------------------------------------
__global__ __launch_bounds__(256)
void dwconv3x3(const unsigned short* __restrict__ X,
               const float* __restrict__ Wd,
               unsigned short* __restrict__ Y,
               long Nn)
{
    __shared__ float P[HWSZ];
    const int ch = blockIdx.x;
    const int z = blockIdx.y;
    const int t = threadIdx.x;
    const unsigned short* xc = X + (long)ch * Nn + (long)z * HWSZ;
#pragma unroll
    for (int l = 0; l < 3; ++l) {
        int q4 = l * 256 + t;
        u16x4 v = *(const u16x4*)&xc[q4 * 4];
        *(float4*)&P[q4 * 4] =
            make_float4(bf2f(v[0]), bf2f(v[1]), bf2f(v[2]), bf2f(v[3]));
    }
    if (t < 16) {
        int q4 = 768 + t;
        u16x4 v = *(const u16x4*)&xc[q4 * 4];
        *(float4*)&P[q4 * 4] =
            make_float4(bf2f(v[0]), bf2f(v[1]), bf2f(v[2]), bf2f(v[3]));
    }
    float w9[9];
#pragma unroll
    for (int q = 0; q < 9; ++q) w9[q] = Wd[ch * 9 + q];
    __syncthreads();

    unsigned short* yc = Y + ((long)z * C3 + ch) * HWSZ;
    const int lane = t & 63;
#pragma unroll
    for (int l = 0; l < 4; ++l) {
        int g4 = l * 256 + t;
        if (g4 < 784) {
            int qi = g4 / 14, qj = g4 - qi * 14;
            float o0 = 0.f, o1 = 0.f, o2 = 0.f, o3 = 0.f;
#pragma unroll
            for (int di = 0; di < 3; ++di) {
                int ii = qi + di - 1;
                if ((unsigned)ii >= HH) continue;
                const float* Pr = &P[ii * WW + qj * 4];
                float4 v = *(const float4*)Pr;
                float lf = __shfl_up(v.w, 1);
                float rt = __shfl_down(v.x, 1);
                if (lane == 0 && qj != 0)   lf = Pr[-1];
                if (lane == 63 && qj != 13) rt = Pr[4];
                if (qj == 0)  lf = 0.f;
                if (qj == 13) rt = 0.f;
                const float wL = w9[di * 3 + 0], wC = w9[di * 3 + 1], wR = w9[di * 3 + 2];
                o0 += wL * lf  + wC * v.x + wR * v.y;
                o1 += wL * v.x + wC * v.y + wR * v.z;
                o2 += wL * v.y + wC * v.z + wR * v.w;
                o3 += wL * v.z + wC * v.w + wR * rt;
            }
            u16x4 ov;
            ov[0] = f2bf(o0); ov[1] = f2bf(o1); ov[2] = f2bf(o2); ov[3] = f2bf(o3);
            *(u16x4*)&yc[g4 * 4] = ov;
        }
    }
}

// ---------------------------------------------------------------------------
// Gram via MFMA: partial Q.K^T + diag norms per (chunk, h, b). grid (7,8,16).
// ---------------------------------------------------------------------------
__global__ __launch_bounds__(256)
void gram_mfma(const unsigned short* __restrict__ dw, float* __restrict__ gram)
{
    __shared__ float Sred[SLAB];
    const int c = blockIdx.x, h = blockIdx.y, b = blockIdx.z;
    const int t = threadIdx.x;
    const int w = t >> 6, lane = t & 63;
    const unsigned short* qb = dw + ((long)b * C3 + h * HD) * HWSZ;
    const unsigned short* kb = dw + ((long)b * C3 + CC + h * HD) * HWSZ;

    for (int l = t; l < SLAB; l += 256) Sred[l] = 0.f;

    const int row = lane & 31;
    const int hi  = lane >> 5;
    const long rbase = (long)row * HWSZ + hi * 8;

    f32x16 aqk, aqq, akk;
#pragma unroll
    for (int i = 0; i < 16; ++i) { aqk[i] = 0.f; aqq[i] = 0.f; akk[i] = 0.f; }

#pragma unroll
    for (int s = 0; s < 7; ++s) {
        int p0 = (c * 28 + w * 7 + s) * 16;
        s16x8 qf = *(const s16x8*)&qb[rbase + p0];
        s16x8 kf = *(const s16x8*)&kb[rbase + p0];
        aqk = __builtin_amdgcn_mfma_f32_32x32x16_bf16(qf, kf, aqk, 0, 0, 0);
        aqq = __builtin_amdgcn_mfma_f32_32x32x16_bf16(qf, qf, aqq, 0, 0, 0);
        akk = __builtin_amdgcn_mfma_f32_32x32x16_bf16(kf, kf, akk, 0, 0, 0);
    }
    __syncthreads();

#pragma unroll
    for (int r = 0; r < 16; ++r) {
        int rowd = (r & 3) + 8 * (r >> 2) + 4 * hi;
        atomicAdd(&Sred[rowd * 32 + row], aqk[r]);
    }
    {
        int dreg = (row & 3) | ((row >> 3) << 2);
        bool has = ((row >> 2) & 1) == hi;
        float qd = has ? aqq[dreg] : 0.f;
        float kd = has ? akk[dreg] : 0.f;
        qd += __shfl_xor(qd, 32);
        kd += __shfl_xor(kd, 32);
        if (hi == 0) {
            atomicAdd(&Sred[1024 + row], qd);
            atomicAdd(&Sred[1056 + row], kd);
        }
    }
    __syncthreads();
    float* slab = gram + (((long)c * BB + b) * HEADS + h) * SLAB;
    for (int l = t; l < SLAB; l += 256) slab[l] = Sred[l];
}

// ---------------------------------------------------------------------------
// Sum slabs, normalize, temperature, softmax over j; write TRANSPOSED
// attn: atT[b][h][j][i] (fp32) for the mprep MFMA B-operand. grid (8,16).
// ---------------------------------------------------------------------------
__global__ __launch_bounds__(1024)
void attn_finish(const float* __restrict__ gram,
                 const float* __restrict__ temp,
                 float* __restrict__ attnT)
{
    __shared__ float nrm[64];
    const int h = blockIdx.x, b = blockIdx.y;
    const int t = threadIdx.x;
    const long sbase = ((long)b * HEADS + h) * SLAB;
    const long cstr  = (long)BB * HEADS * SLAB;
    if (t < 64) {
        float s = 0.f;
#pragma unroll
        for (int c = 0; c < NCHUNK; ++c) s += gram[c * cstr + sbase + 1024 + t];
        nrm[t] = fmaxf(sqrtf(s), EPSF);
    }
    __syncthreads();
    const int i = t >> 5, j = t & 31;
    float s = 0.f;
#pragma unroll
    for (int c = 0; c < NCHUNK; ++c) s += gram[c * cstr + sbase + i * 32 + j];
    s *= temp[h] / (nrm[i] * nrm[32 + j]);
    float mx = s;
    mx = fmaxf(mx, __shfl_xor(mx, 1));
    mx = fmaxf(mx, __shfl_xor(mx, 2));
    mx = fmaxf(mx, __shfl_xor(mx, 4));
    mx = fmaxf(mx, __shfl_xor(mx, 8));
    mx = fmaxf(mx, __shfl_xor(mx, 16));
    float e = expf(s - mx);
    float sum = e;
    sum += __shfl_xor(sum, 1); sum += __shfl_xor(sum, 2);
    sum += __shfl_xor(sum, 4); sum += __shfl_xor(sum, 8);
    sum += __shfl_xor(sum, 16);
    attnT[(((long)b * HEADS + h) * HD + j) * HD + i] = e / sum;
}

// ---------------------------------------------------------------------------
// M[b] = Wp x blockdiag(attn). grid (16), block 256. Output bf16 [256][256].
// ---------------------------------------------------------------------------
__global__ __launch_bounds__(256)
void mprep(const float* __restrict__ Wp,
           const float* __restrict__ atT,
           unsigned short* __restrict__ Mm)
{
    const int zb = blockIdx.x;
    const int t = threadIdx.x, w = t >> 6, lane = t & 63;
    const int lr = lane & 15, gq = lane >> 4;
    const int m_base = w * 64;
    const float* atb = atT + (long)zb * HEADS * HD * HD;
    unsigned short* Mb = Mm + (long)zb * CC * CC;

#pragma unroll
    for (int h = 0; h < 8; ++h) {
        s16x8 bf[2];
#pragma unroll
        for (int jt = 0; jt < 2; ++jt) {
            const float* src = atb + (long)(h * 32 + jt * 16 + lr) * 32 + gq * 8;
            float4 a = *(const float4*)src;
            float4 b = *(const float4*)(src + 4);
            s16x8 v;
            v[0] = (short)f2bf(a.x); v[1] = (short)f2bf(a.y);
            v[2] = (short)f2bf(a.z); v[3] = (short)f2bf(a.w);
            v[4] = (short)f2bf(b.x); v[5] = (short)f2bf(b.y);
            v[6] = (short)f2bf(b.z); v[7] = (short)f2bf(b.w);
            bf[jt] = v;
        }
#pragma unroll
        for (int i = 0; i < 4; ++i) {
            const float* src = Wp + (long)(m_base + i * 16 + lr) * 256 + h * 32 + gq * 8;
            float4 a = *(const float4*)src;
            float4 b = *(const float4*)(src + 4);
            s16x8 af;
            af[0] = (short)f2bf(a.x); af[1] = (short)f2bf(a.y);
            af[2] = (short)f2bf(a.z); af[3] = (short)f2bf(a.w);
            af[4] = (short)f2bf(b.x); af[5] = (short)f2bf(b.y);
            af[6] = (short)f2bf(b.z); af[7] = (short)f2bf(b.w);
#pragma unroll
            for (int jt = 0; jt < 2; ++jt) {
                f32x4 acc = (f32x4){0.f, 0.f, 0.f, 0.f};
                acc = __builtin_amdgcn_mfma_f32_16x16x32_bf16(af, bf[jt], acc, 0, 0, 0);
#pragma unroll
                for (int r = 0; r < 4; ++r)
                    Mb[(long)(m_base + i * 16 + gq * 4 + r) * 256
                       + h * 32 + jt * 16 + lr] = f2bf(acc[r]);
            }
        }
    }
}

// ---------------------------------------------------------------------------
extern "C" void kernel_launch(void* const* d_in, const int* in_sizes, int n_in,
                              void* d_out, int out_size, void* d_ws, size_t ws_size,
                              hipStream_t stream)
{
    const float* x      = (const float*)d_in[0];
    const float* w_qkv  = (const float*)d_in[1];
    const float* w_dw   = (const float*)d_in[2];
    const float* w_proj = (const float*)d_in[3];
    const float* temp   = (const float*)d_in[4];
    float* out = (float*)d_out;
    float* ws  = (float*)d_ws;

    const size_t atF = (size_t)BB * HEADS * HD * HD;           // 131,072 f
    const size_t grF = (size_t)NCHUNK * BB * HEADS * SLAB;     // 974,848 f
    const size_t dwE = (size_t)BB * C3 * HWSZ;                 // u16
    const size_t wqE = (size_t)C3 * CC;                        // u16
    const size_t mmE = (size_t)BB * CC * CC;                   // u16

    float* atT  = ws;
    float* gram = ws + atF;
    unsigned short* dw16 = (unsigned short*)(ws + atF + grF);
    unsigned short* wqb  = dw16 + dwE;
    unsigned short* Mm   = wqb + wqE;
    unsigned short* tmp  = Mm + mmE;

    cvt_w<<<dim3((C3 * CC) / 2048), 256, 0, stream>>>(w_qkv, wqb);

    // qkv: [768 x 50176 x 256], B = x transposed in-kernel. 6*392 = 2352 wgs.
    gemm_tb<0><<<dim3(2352), 256, 0, stream>>>(wqb, x, tmp);

    dwconv3x3<<<dim3(C3, BB), 256, 0, stream>>>(tmp, w_dw, dw16, (long)BB * HWSZ);

    gram_mfma<<<dim3(NCHUNK, HEADS, BB), 256, 0, stream>>>(dw16, gram);
    attn_finish<<<dim3(HEADS, BB), 1024, 0, stream>>>(gram, temp, atT);
    mprep<<<dim3(BB), 256, 0, stream>>>(w_proj, atT, Mm);

    // proj: per-z [256 x 3136 x 256], A = M[z], B = v rows of dw16.
    gemm_tb<1><<<dim3(50, BB), 256, 0, stream>>>(Mm, dw16, out);
}